// Round 4
// baseline (270.895 us; speedup 1.0000x reference)
//
#include <hip/hip_runtime.h>
#include <math.h>

// SpanPairVAHead on MI355X (gfx950).
// Dtype map (established rounds 0-3): ALL float tensors f32, spans int
// (32/64 sniffed on device), OUTPUT f32. Internal activations bf16 for MFMA.
//
// R11: fuse GEMM1 + tail into ONE 256-block kernel with per-m-group soft
// barriers. bid = m*4+z; after writing P the block release-signals cnt[m];
// the tail tile for pairs bid*16.. needs exactly sibling group m = bid>>2,
// so each block acquire-spins on cnt[bid>>2]==4 (3 siblings + itself), then
// runs the tail. No full-grid drain, no launch gap, W3 staging overlaps the
// spin. Deadlock-free: every block signals without waiting; grid 256 <=
// capacity. cnt zeroed by prep (stream-ordered). 2 launches.
// Numerics identical to R10 (absmax canary: 0.03125).
//
// B=64, L=512, H=1024, Q=64, VA_H=256. Pairs = B*Q = 4096.

typedef __attribute__((ext_vector_type(4))) float f32x4;
typedef __attribute__((ext_vector_type(8))) short bf16x8;

#define NPAIR 4096
#define LSEQ 512
#define HDIM 1024

#if defined(__has_builtin)
#if __has_builtin(__builtin_amdgcn_global_load_lds)
#define HAVE_GLDS 1
#endif
#endif
#ifndef HAVE_GLDS
#define HAVE_GLDS 0
#endif

// Pack two f32 -> bf16 pair, round-to-nearest (half-up; differs from RNE only
// on exact ties, p~2^-16). v_perm_b32 grabs the two high halves.
__device__ __forceinline__ unsigned int pack2(float lo, float hi) {
  const unsigned int a = __float_as_uint(lo) + 0x8000u;
  const unsigned int b = __float_as_uint(hi) + 0x8000u;
  return __builtin_amdgcn_perm(b, a, 0x07060302u);
}
__device__ __forceinline__ unsigned short f2bf(float f) {
  return (unsigned short)((__float_as_uint(f) + 0x8000u) >> 16);
}
__device__ __forceinline__ float gelu(float x) {
  return 0.5f * x * (1.f + erff(x * 0.70710678118654752f));
}

// ---------------------------------------------------------------------------
// Merged prep: blocks [0,1024) = fused span pooling via MFMA; blocks
// [1024,1792) = W1 transpose; [1792,1824) = W2 transpose. Block 1024 also
// zeroes the 64 soft-barrier counters for the fused gemm+tail kernel.
// Pool: one block per (batch, 64-col H-slice), 4/CU. Rows 0..63 = asp masks,
// 64..127 = opi. A-frags from span compares in registers; B staged f32->bf16
// transposed ([n][k]) double-buffered, 1 barrier/iter. Epilogue S[128][68].
// ---------------------------------------------------------------------------
__global__ __launch_bounds__(256, 4) void prep_kernel(
    const float* __restrict__ hs, const int* __restrict__ spans,
    const int* __restrict__ qmask, unsigned short* __restrict__ hpair,
    const float* __restrict__ W1, unsigned short* __restrict__ W1T,
    const float* __restrict__ W2, unsigned short* __restrict__ W2T,
    unsigned int* __restrict__ cnt) {
  __shared__ __align__(16) unsigned char smem[34816];  // max(2*64*40*2, 128*68*4)
  __shared__ float scl[128];
  const int tid = threadIdx.x;

  if (blockIdx.x >= 1024) {
    if (blockIdx.x == 1024 && tid < 64) cnt[tid] = 0;  // soft-barrier counters
    // ---- transpose path (f32 in -> bf16 out, transposed) ----
    float(*t)[33] = (float(*)[33])smem;  // 32x33 f32 = 4224 B
    const float* in;
    unsigned short* out;
    int C, R, c0, r0;
    int blk = blockIdx.x - 1024;
    if (blk < 768) {
      in = W1; out = W1T; R = 3072; C = 256;
      c0 = (blk & 7) * 32; r0 = (blk >> 3) * 32;
    } else {
      blk -= 768;
      in = W2; out = W2T; R = 256; C = 128;
      c0 = (blk & 3) * 32; r0 = (blk >> 2) * 32;
    }
    const int x = tid & 31, y = tid >> 5;  // (32, 8)
#pragma unroll
    for (int i = 0; i < 32; i += 8)
      t[y + i][x] = in[(size_t)(r0 + y + i) * C + c0 + x];
    __syncthreads();
#pragma unroll
    for (int i = 0; i < 32; i += 8)
      out[(size_t)(c0 + y + i) * R + r0 + x] = f2bf(t[x][y + i]);
    return;
  }

  // ---- pool path ----
  typedef unsigned short BlT[64][40];
  BlT* Bl = (BlT*)smem;                  // Bl[2][64][40]
  float(*S)[68] = (float(*)[68])smem;    // S[128][68] (epilogue only)

  const int b = blockIdx.x >> 4;
  const int n0 = (blockIdx.x & 15) * 64;
  const int lane = tid & 63;
  const int lm = lane & 15, quad = lane >> 4;
  const int wm = (tid >> 6) * 32;  // wave's mask-row base

  const bool is64 =
      (spans[1] == 0) && (spans[3] == 0) && (spans[5] == 0) && (spans[7] == 0);

  auto span_of = [&](int r, int& s, int& e) {
    const int q = r & 63, t = r >> 6;
    const int idx = (b * 64 + q) * 4 + t * 2;
    s = is64 ? spans[idx * 2] : spans[idx];
    e = is64 ? spans[idx * 2 + 2] : spans[idx + 1];
    if (s < 2) { s = 1; e = 1; }  // invalid -> [SEP]
  };
  int s0, e0, s1, e1;
  span_of(wm + lm, s0, e0);
  span_of(wm + 16 + lm, s1, e1);

  if (tid < 128) {
    int s, e;
    span_of(tid, s, e);
    const int c = (e >= s) ? (e - s + 1) : 0;
    const float sc = 1.f / (float)(c < 1 ? 1 : c);
    scl[tid] = (qmask[b * 64 + (tid & 63)] != 0) ? sc : 0.f;
  }

  f32x4 acc[2][4];
#pragma unroll
  for (int f = 0; f < 2; ++f)
#pragma unroll
    for (int g = 0; g < 4; ++g) acc[f][g] = f32x4{0.f, 0.f, 0.f, 0.f};

  const float* hsb = hs + (size_t)b * (LSEQ * HDIM);
  const int nl = tid & 63;        // staged column (wave-coalesced)
  const int kw = (tid >> 6) * 8;  // wave's k-offset within 32-chunk

  auto load8 = [&](int kbase, unsigned int (&tmp)[4]) {
    const float* src = hsb + (size_t)(kbase + kw) * HDIM + n0 + nl;
#pragma unroll
    for (int i = 0; i < 4; ++i) {
      const float f0 = src[(size_t)(2 * i) * HDIM];
      const float f1 = src[(size_t)(2 * i + 1) * HDIM];
      tmp[i] = pack2(f0, f1);
    }
  };

  unsigned int tmp[4];
  load8(0, tmp);
  *(uint4*)&Bl[0][nl][kw] = make_uint4(tmp[0], tmp[1], tmp[2], tmp[3]);

  for (int it = 0; it < 16; ++it) {
    const int k0 = it * 32;
    __syncthreads();  // buf[it&1] staged; prior reads of buf[(it+1)&1] done
    if (it < 15) load8(k0 + 32, tmp);

    bf16x8 a0, a1;
#pragma unroll
    for (int j = 0; j < 8; ++j) {
      const int k = k0 + quad * 8 + j;
      a0[j] = (short)((k >= s0 && k <= e0) ? 0x3F80 : 0);
      a1[j] = (short)((k >= s1 && k <= e1) ? 0x3F80 : 0);
    }
    const BlT& Bc = Bl[it & 1];
#pragma unroll
    for (int g = 0; g < 4; ++g) {
      bf16x8 bg = *(const bf16x8*)&Bc[g * 16 + lm][quad * 8];
      acc[0][g] = __builtin_amdgcn_mfma_f32_16x16x32_bf16(a0, bg, acc[0][g], 0, 0, 0);
      acc[1][g] = __builtin_amdgcn_mfma_f32_16x16x32_bf16(a1, bg, acc[1][g], 0, 0, 0);
    }
    if (it < 15) {
      *(uint4*)&Bl[(it + 1) & 1][nl][kw] = make_uint4(tmp[0], tmp[1], tmp[2], tmp[3]);
    }
  }

  __syncthreads();  // all MFMA LDS reads done before S overwrites Bl
  // C/D layout (m89): col = lane&15, row = quad*4 + reg.
#pragma unroll
  for (int f = 0; f < 2; ++f)
#pragma unroll
    for (int g = 0; g < 4; ++g)
#pragma unroll
      for (int r = 0; r < 4; ++r)
        S[wm + f * 16 + quad * 4 + r][g * 16 + lm] = acc[f][g][r];
  __syncthreads();

  // Store h_pair: thread q = tid>>2, 16-col group cg = (tid&3)*16.
  const int q = tid >> 2;
  const int cg = (tid & 3) * 16;
  const float sA = scl[q], sO = scl[64 + q];
  unsigned short* dst = hpair + (size_t)(b * 64 + q) * 3072 + n0 + cg;
#pragma unroll
  for (int h = 0; h < 2; ++h) {
    float a[8], o[8];
#pragma unroll
    for (int i = 0; i < 8; ++i) {
      a[i] = S[q][cg + h * 8 + i] * sA;
      o[i] = S[64 + q][cg + h * 8 + i] * sO;
    }
    uint4 wa, wo, wp;
    wa.x = pack2(a[0], a[1]); wa.y = pack2(a[2], a[3]);
    wa.z = pack2(a[4], a[5]); wa.w = pack2(a[6], a[7]);
    wo.x = pack2(o[0], o[1]); wo.y = pack2(o[2], o[3]);
    wo.z = pack2(o[4], o[5]); wo.w = pack2(o[6], o[7]);
    wp.x = pack2(a[0] * o[0], a[1] * o[1]); wp.y = pack2(a[2] * o[2], a[3] * o[3]);
    wp.z = pack2(a[4] * o[4], a[5] * o[5]); wp.w = pack2(a[6] * o[6], a[7] * o[7]);
    *(uint4*)(dst + h * 8) = wa;
    *(uint4*)(dst + 1024 + h * 8) = wo;
    *(uint4*)(dst + 2048 + h * 8) = wp;
  }
}

// ---------------------------------------------------------------------------
// Fused GEMM1 + tail, 256 blocks (1/CU). bid = m*4+z.
// Phase 1 (GEMM): P[z][rows 64m..] = A slice @ W1T^T, 64x256 tile, BK=32,
// 4 waves side-by-side in N (per-wave 64x64, 4x4 frags), global_load_lds
// w=16, double-buffered, stage-before-compute, one barrier/K-step.
// Then: threadfence + release atomicAdd(cnt[m]).
// Phase 2 (tail): spin until cnt[bid>>2]==4 (its own sibling group), then
// split-K reduce + b1 + gelu -> x1 LDS tile, GEMM2 (16x128, K=256) with
// B-frags from W2T global, gelu+b2 -> S2, head dot W3, sigmoid*8+1, *qmask.
// LDS unioned: gemm 40KB, tail 17.5KB.
// ---------------------------------------------------------------------------
__global__ __launch_bounds__(256) void gemm_tail_kernel(
    const unsigned short* __restrict__ A, const unsigned short* __restrict__ Bt,
    float* __restrict__ P, const float* __restrict__ b1,
    const unsigned short* __restrict__ W2T, const float* __restrict__ b2,
    const float* __restrict__ W3, const float* __restrict__ b3,
    const int* __restrict__ qmask, float* __restrict__ out,
    unsigned int* __restrict__ cnt) {
  __shared__ __align__(16) unsigned char smem[40960];
  const int tid = threadIdx.x;
  const int wave = tid >> 6, lane = tid & 63;
  const int lm = lane & 15, quad = lane >> 4;

  const int m = blockIdx.x >> 2, z = blockIdx.x & 3;
  const int K = 3072, N = 256, KH = 768;

  // ===== Phase 1: GEMM1 partial =====
  {
    typedef unsigned short AlT[64][32];
    typedef unsigned short BlT[256][32];
    AlT* Al = (AlT*)smem;                  // Al[2]: 8 KB
    BlT* Bl = (BlT*)(smem + 8192);         // Bl[2]: 32 KB
    const int bm = m * 64;
    const int kz = z * KH;
    const int wn = wave * 64;  // wave's N-slice
    const int lk = (lane >> 4) * 8;

    const int srow = lane >> 2;          // 0..15
    const int scol = (lane & 3) * 8;
    const unsigned short* ga = A + (size_t)(bm + wave * 16 + srow) * K + kz + scol;
    const unsigned short* gb = Bt + (size_t)(wn + srow) * K + kz + scol;

    f32x4 acc[4][4];
#pragma unroll
    for (int i = 0; i < 4; ++i)
#pragma unroll
      for (int j = 0; j < 4; ++j) acc[i][j] = f32x4{0.f, 0.f, 0.f, 0.f};

    auto stage = [&](int u, int k0) {
#if HAVE_GLDS
      __builtin_amdgcn_global_load_lds(ga + k0, &Al[u][wave * 16][0], 16, 0, 0);
#pragma unroll
      for (int c = 0; c < 4; ++c)
        __builtin_amdgcn_global_load_lds(gb + (size_t)(c * 16) * K + k0,
                                         &Bl[u][wn + c * 16][0], 16, 0, 0);
#else
      *(uint4*)&Al[u][wave * 16 + srow][scol] = *(const uint4*)(ga + k0);
#pragma unroll
      for (int c = 0; c < 4; ++c)
        *(uint4*)&Bl[u][wn + c * 16 + srow][scol] =
            *(const uint4*)(gb + (size_t)(c * 16) * K + k0);
#endif
    };

    const int NT = KH / 32;  // 24
    stage(0, 0);
    for (int t = 0; t < NT; ++t) {
      __syncthreads();  // buf[t&1] staged (vmcnt drained); prior buf reads done
      if (t + 1 < NT) stage((t + 1) & 1, (t + 1) * 32);
      const int u = t & 1;
      bf16x8 af[4], bf[4];
#pragma unroll
      for (int i = 0; i < 4; ++i) {
        af[i] = *(const bf16x8*)&Al[u][i * 16 + lm][lk];
        bf[i] = *(const bf16x8*)&Bl[u][wn + i * 16 + lm][lk];
      }
#pragma unroll
      for (int i = 0; i < 4; ++i)
#pragma unroll
        for (int j = 0; j < 4; ++j)
          acc[i][j] = __builtin_amdgcn_mfma_f32_16x16x32_bf16(af[i], bf[j], acc[i][j], 0, 0, 0);
    }

    float* Pz = P + (size_t)z * NPAIR * N;
    const int rq = (lane >> 4) << 2;
#pragma unroll
    for (int i = 0; i < 4; ++i)
#pragma unroll
      for (int j = 0; j < 4; ++j) {
        const int r0 = bm + i * 16 + rq;
        const int c0 = wn + j * 16 + lm;
#pragma unroll
        for (int r = 0; r < 4; ++r)
          Pz[(size_t)(r0 + r) * N + c0] = acc[i][j][r];
      }
  }

  // ===== Soft barrier: release P, wait for sibling group =====
  __threadfence();   // P stores device-visible before the signal
  __syncthreads();   // all waves' stores + fences precede thread 0's signal
  // Tail LDS layout (safe to write now: all gemm LDS reads are behind the
  // barrier above): Ax @0 (8448B), S2 @8448 (8448B), w3 @16896 (1024B).
  unsigned short* Ax = (unsigned short*)smem;
  float(*S2)[132] = (float(*)[132])(smem + 8448);
  float* w3 = (float*)(smem + 16896);
  w3[tid] = W3[tid];  // overlaps the spin

  if (tid == 0) {
    __hip_atomic_fetch_add(&cnt[m], 1u, __ATOMIC_RELEASE,
                           __HIP_MEMORY_SCOPE_AGENT);
    while (__hip_atomic_load(&cnt[m], __ATOMIC_ACQUIRE,
                             __HIP_MEMORY_SCOPE_AGENT) < 4u) {
      __builtin_amdgcn_s_sleep(8);
    }
  }
  __syncthreads();
  // Per-thread acquire so every wave's subsequent P loads see released data.
  (void)__hip_atomic_load(&cnt[m], __ATOMIC_ACQUIRE, __HIP_MEMORY_SCOPE_AGENT);

  // ===== Phase 2: tail for pairs [bid*16, bid*16+16) =====
  const int m0 = blockIdx.x * 16;
  const int wn2 = wave * 32;  // wave's 32-col slice of N=128

  // Stage x1 tile: x1[r][k] = gelu(sum_z P[z] + b1). 16 elems/thread.
  {
    const int row = tid >> 4;   // 0..15
    const int slot = tid & 15;  // 8-elem slot
#pragma unroll
    for (int ss = 0; ss < 2; ++ss) {
      const int s = slot + ss * 16;  // 0..31
      const float* pb = P + (size_t)(m0 + row) * 256 + s * 8;
      float v[8];
      {
        float4 ba = *(const float4*)(b1 + s * 8);
        float4 bb = *(const float4*)(b1 + s * 8 + 4);
        v[0] = ba.x; v[1] = ba.y; v[2] = ba.z; v[3] = ba.w;
        v[4] = bb.x; v[5] = bb.y; v[6] = bb.z; v[7] = bb.w;
      }
#pragma unroll
      for (int zz = 0; zz < 4; ++zz) {
        const float* pz = pb + (size_t)zz * ((size_t)NPAIR * 256);
        float4 a0 = *(const float4*)pz;
        float4 a1 = *(const float4*)(pz + 4);
        v[0] += a0.x; v[1] += a0.y; v[2] += a0.z; v[3] += a0.w;
        v[4] += a1.x; v[5] += a1.y; v[6] += a1.z; v[7] += a1.w;
      }
      uint4 w;
      w.x = pack2(gelu(v[0]), gelu(v[1]));
      w.y = pack2(gelu(v[2]), gelu(v[3]));
      w.z = pack2(gelu(v[4]), gelu(v[5]));
      w.w = pack2(gelu(v[6]), gelu(v[7]));
      *(uint4*)((char*)Ax + (size_t)row * 528 + s * 16) = w;
    }
  }
  __syncthreads();  // Ax ready; LDS read-only from here

  // GEMM2: M=16 (1 frag), N=128 (2 frags/wave), K=256 (8 steps).
  // B-frags straight from W2T[n][k] global (L2-resident).
  f32x4 acc2[2];
  acc2[0] = f32x4{0.f, 0.f, 0.f, 0.f};
  acc2[1] = f32x4{0.f, 0.f, 0.f, 0.f};
#pragma unroll
  for (int ks = 0; ks < 8; ++ks) {
    bf16x8 a = *(const bf16x8*)((char*)Ax + (size_t)lm * 528 + ks * 64 + quad * 16);
#pragma unroll
    for (int g = 0; g < 2; ++g) {
      const int n = wn2 + g * 16 + lm;
      bf16x8 b = *(const bf16x8*)(W2T + (size_t)n * 256 + ks * 32 + quad * 8);
      acc2[g] = __builtin_amdgcn_mfma_f32_16x16x32_bf16(a, b, acc2[g], 0, 0, 0);
    }
  }

  // x2 = gelu(acc + b2). C/D: col = lane&15, row = quad*4 + reg.
#pragma unroll
  for (int g = 0; g < 2; ++g) {
    const int col = wn2 + g * 16 + lm;
    const float bc = b2[col];
#pragma unroll
    for (int r = 0; r < 4; ++r) S2[quad * 4 + r][col] = gelu(acc2[g][r] + bc);
  }
  __syncthreads();

  // Head: 128 threads, (row, o) each split 4-way over K=128, shfl-reduce.
  if (tid < 128) {
    const int row = tid >> 3, o = (tid >> 2) & 1, q4 = tid & 3;
    float part = 0.f;
#pragma unroll 8
    for (int c = q4; c < 128; c += 4) part += S2[row][c] * w3[c * 2 + o];
    part += __shfl_xor(part, 1);
    part += __shfl_xor(part, 2);
    if (q4 == 0) {
      const int pair = m0 + row;
      const float a = part + b3[o];
      const float qmf = (float)qmask[pair];
      out[pair * 2 + o] = ((1.f / (1.f + expf(-a))) * 8.f + 1.f) * qmf;
    }
  }
}

// ---------------------------------------------------------------------------
extern "C" void kernel_launch(void* const* d_in, const int* in_sizes, int n_in,
                              void* d_out, int out_size, void* d_ws,
                              size_t ws_size, hipStream_t stream) {
  const float* hs = (const float*)d_in[0];   // f32 64x512x1024
  const int* spans = (const int*)d_in[1];
  const int* qmask = (const int*)d_in[2];
  const float* W1 = (const float*)d_in[3];   // f32 3072x256
  const float* b1 = (const float*)d_in[4];
  const float* W2 = (const float*)d_in[5];   // f32 256x128
  const float* b2 = (const float*)d_in[6];
  const float* W3 = (const float*)d_in[7];   // f32 128x2
  const float* b3 = (const float*)d_in[8];
  float* out = (float*)d_out;

  const size_t HPAIR_B = 25165824;  // 4096*3072 bf16
  const size_t P_B = 16777216;      // 4 x 4096*256 f32
  const size_t W1T_B = 1572864;     // 256*3072 bf16
  const size_t W2T_B = 65536;       // 128*256 bf16

  char* ws = (char*)d_ws;
  size_t off = 0;
  unsigned short* hpair = (unsigned short*)(ws + off); off += HPAIR_B;
  float* P = (float*)(ws + off);                       off += P_B;
  unsigned short* W1T = (unsigned short*)(ws + off);   off += W1T_B;
  unsigned short* W2T = (unsigned short*)(ws + off);   off += W2T_B;
  unsigned int* cnt = (unsigned int*)(ws + off);       // 64 counters

  prep_kernel<<<1824, 256, 0, stream>>>(hs, spans, qmask, hpair, W1, W1T, W2,
                                        W2T, cnt);
  gemm_tail_kernel<<<256, 256, 0, stream>>>(hpair, W1T, P, b1, W2T, b2, W3,
                                            b3, qmask, out, cnt);
}

// Round 5
// 237.135 us; speedup vs baseline: 1.1424x; 1.1424x over previous
//
#include <hip/hip_runtime.h>
#include <math.h>

// SpanPairVAHead on MI355X (gfx950).
// Dtype map (established rounds 0-3): ALL float tensors f32, spans int
// (32/64 sniffed on device), OUTPUT f32. Internal activations bf16 for MFMA.
//
// R12: revert R11's in-kernel soft barrier (agent-scope acquire polling
// invalidates the XCD L2 under sibling blocks -> latency storm; measured
// 78us @ 3% MfmaUtil). Back to R10's 3-launch structure. GEMM1 occupancy
// fix: split-K z=4 -> z=8 (KH=384, grid 512 = 2 blocks/CU,
// __launch_bounds__(256,2)) so one block's staging hides under the other's
// compute (m114 wave-overlap needs >=2 blocks/CU). Tail reduces 8 partials.
//
// B=64, L=512, H=1024, Q=64, VA_H=256. Pairs = B*Q = 4096.

typedef __attribute__((ext_vector_type(4))) float f32x4;
typedef __attribute__((ext_vector_type(8))) short bf16x8;

#define NPAIR 4096
#define LSEQ 512
#define HDIM 1024
#define ZSPLIT 8

#if defined(__has_builtin)
#if __has_builtin(__builtin_amdgcn_global_load_lds)
#define HAVE_GLDS 1
#endif
#endif
#ifndef HAVE_GLDS
#define HAVE_GLDS 0
#endif

// Pack two f32 -> bf16 pair, round-to-nearest (half-up; differs from RNE only
// on exact ties, p~2^-16). v_perm_b32 grabs the two high halves.
__device__ __forceinline__ unsigned int pack2(float lo, float hi) {
  const unsigned int a = __float_as_uint(lo) + 0x8000u;
  const unsigned int b = __float_as_uint(hi) + 0x8000u;
  return __builtin_amdgcn_perm(b, a, 0x07060302u);
}
__device__ __forceinline__ unsigned short f2bf(float f) {
  return (unsigned short)((__float_as_uint(f) + 0x8000u) >> 16);
}
__device__ __forceinline__ float gelu(float x) {
  return 0.5f * x * (1.f + erff(x * 0.70710678118654752f));
}

// ---------------------------------------------------------------------------
// Merged prep: blocks [0,1024) = fused span pooling via MFMA; blocks
// [1024,1792) = W1 transpose; [1792,1824) = W2 transpose.
// Pool: one block per (batch, 64-col H-slice), 4/CU. Rows 0..63 = asp masks,
// 64..127 = opi. A-frags from span compares in registers; B staged f32->bf16
// transposed ([n][k]) double-buffered, 1 barrier/iter. Epilogue S[128][68].
// ---------------------------------------------------------------------------
__global__ __launch_bounds__(256, 4) void prep_kernel(
    const float* __restrict__ hs, const int* __restrict__ spans,
    const int* __restrict__ qmask, unsigned short* __restrict__ hpair,
    const float* __restrict__ W1, unsigned short* __restrict__ W1T,
    const float* __restrict__ W2, unsigned short* __restrict__ W2T) {
  __shared__ __align__(16) unsigned char smem[34816];  // max(2*64*40*2, 128*68*4)
  __shared__ float scl[128];
  const int tid = threadIdx.x;

  if (blockIdx.x >= 1024) {
    // ---- transpose path (f32 in -> bf16 out, transposed) ----
    float(*t)[33] = (float(*)[33])smem;  // 32x33 f32 = 4224 B
    const float* in;
    unsigned short* out;
    int C, R, c0, r0;
    int blk = blockIdx.x - 1024;
    if (blk < 768) {
      in = W1; out = W1T; R = 3072; C = 256;
      c0 = (blk & 7) * 32; r0 = (blk >> 3) * 32;
    } else {
      blk -= 768;
      in = W2; out = W2T; R = 256; C = 128;
      c0 = (blk & 3) * 32; r0 = (blk >> 2) * 32;
    }
    const int x = tid & 31, y = tid >> 5;  // (32, 8)
#pragma unroll
    for (int i = 0; i < 32; i += 8)
      t[y + i][x] = in[(size_t)(r0 + y + i) * C + c0 + x];
    __syncthreads();
#pragma unroll
    for (int i = 0; i < 32; i += 8)
      out[(size_t)(c0 + y + i) * R + r0 + x] = f2bf(t[x][y + i]);
    return;
  }

  // ---- pool path ----
  typedef unsigned short BlT[64][40];
  BlT* Bl = (BlT*)smem;                  // Bl[2][64][40]
  float(*S)[68] = (float(*)[68])smem;    // S[128][68] (epilogue only)

  const int b = blockIdx.x >> 4;
  const int n0 = (blockIdx.x & 15) * 64;
  const int lane = tid & 63;
  const int lm = lane & 15, quad = lane >> 4;
  const int wm = (tid >> 6) * 32;  // wave's mask-row base

  const bool is64 =
      (spans[1] == 0) && (spans[3] == 0) && (spans[5] == 0) && (spans[7] == 0);

  auto span_of = [&](int r, int& s, int& e) {
    const int q = r & 63, t = r >> 6;
    const int idx = (b * 64 + q) * 4 + t * 2;
    s = is64 ? spans[idx * 2] : spans[idx];
    e = is64 ? spans[idx * 2 + 2] : spans[idx + 1];
    if (s < 2) { s = 1; e = 1; }  // invalid -> [SEP]
  };
  int s0, e0, s1, e1;
  span_of(wm + lm, s0, e0);
  span_of(wm + 16 + lm, s1, e1);

  if (tid < 128) {
    int s, e;
    span_of(tid, s, e);
    const int c = (e >= s) ? (e - s + 1) : 0;
    const float sc = 1.f / (float)(c < 1 ? 1 : c);
    scl[tid] = (qmask[b * 64 + (tid & 63)] != 0) ? sc : 0.f;
  }

  f32x4 acc[2][4];
#pragma unroll
  for (int f = 0; f < 2; ++f)
#pragma unroll
    for (int g = 0; g < 4; ++g) acc[f][g] = f32x4{0.f, 0.f, 0.f, 0.f};

  const float* hsb = hs + (size_t)b * (LSEQ * HDIM);
  const int nl = tid & 63;        // staged column (wave-coalesced)
  const int kw = (tid >> 6) * 8;  // wave's k-offset within 32-chunk

  auto load8 = [&](int kbase, unsigned int (&tmp)[4]) {
    const float* src = hsb + (size_t)(kbase + kw) * HDIM + n0 + nl;
#pragma unroll
    for (int i = 0; i < 4; ++i) {
      const float f0 = src[(size_t)(2 * i) * HDIM];
      const float f1 = src[(size_t)(2 * i + 1) * HDIM];
      tmp[i] = pack2(f0, f1);
    }
  };

  unsigned int tmp[4];
  load8(0, tmp);
  *(uint4*)&Bl[0][nl][kw] = make_uint4(tmp[0], tmp[1], tmp[2], tmp[3]);

  for (int it = 0; it < 16; ++it) {
    const int k0 = it * 32;
    __syncthreads();  // buf[it&1] staged; prior reads of buf[(it+1)&1] done
    if (it < 15) load8(k0 + 32, tmp);

    bf16x8 a0, a1;
#pragma unroll
    for (int j = 0; j < 8; ++j) {
      const int k = k0 + quad * 8 + j;
      a0[j] = (short)((k >= s0 && k <= e0) ? 0x3F80 : 0);
      a1[j] = (short)((k >= s1 && k <= e1) ? 0x3F80 : 0);
    }
    const BlT& Bc = Bl[it & 1];
#pragma unroll
    for (int g = 0; g < 4; ++g) {
      bf16x8 bg = *(const bf16x8*)&Bc[g * 16 + lm][quad * 8];
      acc[0][g] = __builtin_amdgcn_mfma_f32_16x16x32_bf16(a0, bg, acc[0][g], 0, 0, 0);
      acc[1][g] = __builtin_amdgcn_mfma_f32_16x16x32_bf16(a1, bg, acc[1][g], 0, 0, 0);
    }
    if (it < 15) {
      *(uint4*)&Bl[(it + 1) & 1][nl][kw] = make_uint4(tmp[0], tmp[1], tmp[2], tmp[3]);
    }
  }

  __syncthreads();  // all MFMA LDS reads done before S overwrites Bl
  // C/D layout (m89): col = lane&15, row = quad*4 + reg.
#pragma unroll
  for (int f = 0; f < 2; ++f)
#pragma unroll
    for (int g = 0; g < 4; ++g)
#pragma unroll
      for (int r = 0; r < 4; ++r)
        S[wm + f * 16 + quad * 4 + r][g * 16 + lm] = acc[f][g][r];
  __syncthreads();

  // Store h_pair: thread q = tid>>2, 16-col group cg = (tid&3)*16.
  const int q = tid >> 2;
  const int cg = (tid & 3) * 16;
  const float sA = scl[q], sO = scl[64 + q];
  unsigned short* dst = hpair + (size_t)(b * 64 + q) * 3072 + n0 + cg;
#pragma unroll
  for (int h = 0; h < 2; ++h) {
    float a[8], o[8];
#pragma unroll
    for (int i = 0; i < 8; ++i) {
      a[i] = S[q][cg + h * 8 + i] * sA;
      o[i] = S[64 + q][cg + h * 8 + i] * sO;
    }
    uint4 wa, wo, wp;
    wa.x = pack2(a[0], a[1]); wa.y = pack2(a[2], a[3]);
    wa.z = pack2(a[4], a[5]); wa.w = pack2(a[6], a[7]);
    wo.x = pack2(o[0], o[1]); wo.y = pack2(o[2], o[3]);
    wo.z = pack2(o[4], o[5]); wo.w = pack2(o[6], o[7]);
    wp.x = pack2(a[0] * o[0], a[1] * o[1]); wp.y = pack2(a[2] * o[2], a[3] * o[3]);
    wp.z = pack2(a[4] * o[4], a[5] * o[5]); wp.w = pack2(a[6] * o[6], a[7] * o[7]);
    *(uint4*)(dst + h * 8) = wa;
    *(uint4*)(dst + 1024 + h * 8) = wo;
    *(uint4*)(dst + 2048 + h * 8) = wp;
  }
}

// ---------------------------------------------------------------------------
// Split-K GEMM1 partial, 64x256 tile (full N in one block): P[z] = A slice @
// Bt^T. BK=32, 4 waves side-by-side in N (per-wave tile 64x64, 4x4 16x16
// frags). z=8 split: grid (64,1,8) = 512 blocks = 2 blocks/CU — one block's
// global_load_lds staging hides under the co-resident block's ds_read+MFMA
// (m114 overlap). KH=384 -> 12 K-steps. LDS 40 KB (2 blocks = 80 <= 160).
// global_load_lds w=16 into double-buffered unpadded LDS (wave-uniform dest
// + lane*16, m104). Stage(t+1) before compute(t); one barrier per K-step.
// ---------------------------------------------------------------------------
__global__ __launch_bounds__(256, 2) void gemm_bt_64x256(
    const unsigned short* __restrict__ A, const unsigned short* __restrict__ Bt,
    float* __restrict__ P, int M, int N, int K, int KH) {
  __shared__ __align__(16) unsigned short Al[2][64][32];
  __shared__ __align__(16) unsigned short Bl[2][256][32];
  const int bm = blockIdx.x * 64;
  const int kz = blockIdx.z * KH;
  const int tid = threadIdx.x;
  const int wave = tid >> 6, lane = tid & 63;
  const int wn = wave * 64;  // wave's N-slice
  const int lm = lane & 15, lk = (lane >> 4) * 8;

  // Staging: wave stages A rows [wave*16, wave*16+16) (1 call) and B rows
  // [wave*64, wave*64+64) (4 calls). Each call: 16 rows x 32 cols = 1 KB.
  const int srow = lane >> 2;          // 0..15
  const int scol = (lane & 3) * 8;
  const unsigned short* ga = A + (size_t)(bm + wave * 16 + srow) * K + kz + scol;
  const unsigned short* gb = Bt + (size_t)(wn + srow) * K + kz + scol;

  f32x4 acc[4][4];
#pragma unroll
  for (int i = 0; i < 4; ++i)
#pragma unroll
    for (int j = 0; j < 4; ++j) acc[i][j] = f32x4{0.f, 0.f, 0.f, 0.f};

  auto stage = [&](int u, int k0) {
#if HAVE_GLDS
    __builtin_amdgcn_global_load_lds(ga + k0, &Al[u][wave * 16][0], 16, 0, 0);
#pragma unroll
    for (int c = 0; c < 4; ++c)
      __builtin_amdgcn_global_load_lds(gb + (size_t)(c * 16) * K + k0,
                                       &Bl[u][wn + c * 16][0], 16, 0, 0);
#else
    *(uint4*)&Al[u][wave * 16 + srow][scol] = *(const uint4*)(ga + k0);
#pragma unroll
    for (int c = 0; c < 4; ++c)
      *(uint4*)&Bl[u][wn + c * 16 + srow][scol] =
          *(const uint4*)(gb + (size_t)(c * 16) * K + k0);
#endif
  };

  const int NT = KH / 32;  // 12
  stage(0, 0);
  for (int t = 0; t < NT; ++t) {
    __syncthreads();  // buf[t&1] staged (vmcnt drained); prior buf reads done
    if (t + 1 < NT) stage((t + 1) & 1, (t + 1) * 32);
    const int u = t & 1;
    bf16x8 af[4], bf[4];
#pragma unroll
    for (int i = 0; i < 4; ++i) {
      af[i] = *(const bf16x8*)&Al[u][i * 16 + lm][lk];
      bf[i] = *(const bf16x8*)&Bl[u][wn + i * 16 + lm][lk];
    }
#pragma unroll
    for (int i = 0; i < 4; ++i)
#pragma unroll
      for (int j = 0; j < 4; ++j)
        acc[i][j] = __builtin_amdgcn_mfma_f32_16x16x32_bf16(af[i], bf[j], acc[i][j], 0, 0, 0);
  }

  float* Pz = P + (size_t)blockIdx.z * M * N;
  const int rq = (lane >> 4) << 2;
#pragma unroll
  for (int i = 0; i < 4; ++i)
#pragma unroll
    for (int j = 0; j < 4; ++j) {
      const int r0 = bm + i * 16 + rq;
      const int c0 = wn + j * 16 + lm;
#pragma unroll
      for (int r = 0; r < 4; ++r)
        Pz[(size_t)(r0 + r) * N + c0] = acc[i][j][r];
    }
}

// ---------------------------------------------------------------------------
// Fused tail: split-K reduce (8 partials) + b1 + gelu -> x1 tile (LDS),
// GEMM2 (16x128, K=256) with B-frags from W2T global (L2-resident),
// gelu+b2 -> S2, head dot W3, sigmoid*8+1, *qmask.
// 256 blocks x 16 pairs = 1 block/CU. ONE barrier before the K-loop.
// ---------------------------------------------------------------------------
__global__ __launch_bounds__(256) void tail_kernel(
    const float* __restrict__ P, const float* __restrict__ b1,
    const unsigned short* __restrict__ W2T, const float* __restrict__ b2,
    const float* __restrict__ W3, const float* __restrict__ b3,
    const int* __restrict__ qmask, float* __restrict__ out) {
  __shared__ __align__(16) unsigned short Al[16 * 264];  // x1 tile, 528B rows
  __shared__ float S2[16][132];                          // x2 tile f32
  __shared__ float w3[256];

  const int m0 = blockIdx.x * 16;
  const int tid = threadIdx.x;
  const int wave = tid >> 6, lane = tid & 63;
  const int lm = lane & 15, quad = lane >> 4;
  const int wn = wave * 32;  // wave's 32-col slice of N=128

  w3[tid] = W3[tid];  // 128x2 f32

  // --- Stage x1 tile: x1[r][k] = gelu(sum_z P[z] + b1). 16 elems/thread,
  // coalesced float4 reads of P.
  {
    const int row = tid >> 4;   // 0..15
    const int slot = tid & 15;  // 8-elem slot
#pragma unroll
    for (int ss = 0; ss < 2; ++ss) {
      const int s = slot + ss * 16;  // 0..31
      const float* pb = P + (size_t)(m0 + row) * 256 + s * 8;
      float v[8];
      {
        float4 ba = *(const float4*)(b1 + s * 8);
        float4 bb = *(const float4*)(b1 + s * 8 + 4);
        v[0] = ba.x; v[1] = ba.y; v[2] = ba.z; v[3] = ba.w;
        v[4] = bb.x; v[5] = bb.y; v[6] = bb.z; v[7] = bb.w;
      }
#pragma unroll
      for (int z = 0; z < ZSPLIT; ++z) {
        const float* pz = pb + (size_t)z * ((size_t)NPAIR * 256);
        float4 a0 = *(const float4*)pz;
        float4 a1 = *(const float4*)(pz + 4);
        v[0] += a0.x; v[1] += a0.y; v[2] += a0.z; v[3] += a0.w;
        v[4] += a1.x; v[5] += a1.y; v[6] += a1.z; v[7] += a1.w;
      }
      uint4 w;
      w.x = pack2(gelu(v[0]), gelu(v[1]));
      w.y = pack2(gelu(v[2]), gelu(v[3]));
      w.z = pack2(gelu(v[4]), gelu(v[5]));
      w.w = pack2(gelu(v[6]), gelu(v[7]));
      *(uint4*)((char*)Al + (size_t)row * 528 + s * 16) = w;
    }
  }
  __syncthreads();  // Al ready; LDS read-only from here

  // --- GEMM2: M=16 (1 frag), N=128 (2 frags/wave), K=256 (8 steps).
  // B-frags straight from W2T[n][k] global (row n = wn+g*16+lm, 16B-aligned).
  f32x4 acc[2];
  acc[0] = f32x4{0.f, 0.f, 0.f, 0.f};
  acc[1] = f32x4{0.f, 0.f, 0.f, 0.f};
#pragma unroll
  for (int ks = 0; ks < 8; ++ks) {
    bf16x8 a = *(const bf16x8*)((char*)Al + (size_t)lm * 528 + ks * 64 + quad * 16);
#pragma unroll
    for (int g = 0; g < 2; ++g) {
      const int n = wn + g * 16 + lm;
      bf16x8 b = *(const bf16x8*)(W2T + (size_t)n * 256 + ks * 32 + quad * 8);
      acc[g] = __builtin_amdgcn_mfma_f32_16x16x32_bf16(a, b, acc[g], 0, 0, 0);
    }
  }

  // --- x2 = gelu(acc + b2). C/D: col = lane&15, row = quad*4 + reg.
#pragma unroll
  for (int g = 0; g < 2; ++g) {
    const int col = wn + g * 16 + lm;
    const float bc = b2[col];
#pragma unroll
    for (int r = 0; r < 4; ++r) S2[quad * 4 + r][col] = gelu(acc[g][r] + bc);
  }
  __syncthreads();

  // --- Head: 128 threads, (row, o) each split 4-way over K=128, shfl-reduce.
  if (tid < 128) {
    const int row = tid >> 3, o = (tid >> 2) & 1, q4 = tid & 3;
    float part = 0.f;
#pragma unroll 8
    for (int c = q4; c < 128; c += 4) part += S2[row][c] * w3[c * 2 + o];
    part += __shfl_xor(part, 1);
    part += __shfl_xor(part, 2);
    if (q4 == 0) {
      const int pair = m0 + row;
      const float a = part + b3[o];
      const float qmf = (float)qmask[pair];
      out[pair * 2 + o] = ((1.f / (1.f + expf(-a))) * 8.f + 1.f) * qmf;
    }
  }
}

// ---------------------------------------------------------------------------
extern "C" void kernel_launch(void* const* d_in, const int* in_sizes, int n_in,
                              void* d_out, int out_size, void* d_ws,
                              size_t ws_size, hipStream_t stream) {
  const float* hs = (const float*)d_in[0];   // f32 64x512x1024
  const int* spans = (const int*)d_in[1];
  const int* qmask = (const int*)d_in[2];
  const float* W1 = (const float*)d_in[3];   // f32 3072x256
  const float* b1 = (const float*)d_in[4];
  const float* W2 = (const float*)d_in[5];   // f32 256x128
  const float* b2 = (const float*)d_in[6];
  const float* W3 = (const float*)d_in[7];   // f32 128x2
  const float* b3 = (const float*)d_in[8];
  float* out = (float*)d_out;

  const size_t HPAIR_B = 25165824;  // 4096*3072 bf16
  const size_t P_B = 33554432;      // 8 x 4096*256 f32
  const size_t W1T_B = 1572864;     // 256*3072 bf16

  char* ws = (char*)d_ws;
  size_t off = 0;
  unsigned short* hpair = (unsigned short*)(ws + off); off += HPAIR_B;
  float* P = (float*)(ws + off);                       off += P_B;
  unsigned short* W1T = (unsigned short*)(ws + off);   off += W1T_B;
  unsigned short* W2T = (unsigned short*)(ws + off);

  prep_kernel<<<1824, 256, 0, stream>>>(hs, spans, qmask, hpair, W1, W1T, W2, W2T);
  gemm_bt_64x256<<<dim3(64, 1, ZSPLIT), 256, 0, stream>>>(hpair, W1T, P, NPAIR,
                                                          256, 3072, 384);
  tail_kernel<<<256, 256, 0, stream>>>(P, b1, W2T, b2, W3, b3, qmask, out);
}

// Round 6
// 235.964 us; speedup vs baseline: 1.1480x; 1.0050x over previous
//
#include <hip/hip_runtime.h>
#include <math.h>

// SpanPairVAHead on MI355X (gfx950).
// Dtype map (established rounds 0-3): ALL float tensors f32, spans int
// (32/64 sniffed on device), OUTPUT f32. Internal activations bf16 for MFMA.
//
// R13: GEMM1 K-loop rebuilt with counted vmcnt (T3+T4 minimum). Insight from
// R9/R10/R12 neutrality: all configs share 6144 block-iters each with a
// __syncthreads() whose implicit vmcnt(0) drains the just-issued prefetch
// (~200cy of cover for ~600-900cy latency -> ~400cy stall/iter, invariant
// across tile shape & occupancy). Fix: 3-buffer LDS ring, prefetch depth 2,
// raw s_barrier + s_waitcnt vmcnt(5) (one 5-load stage in flight; vmcnt(0)
// only on the last iter). lgkmcnt(0)+sched_barrier before barrier#2 makes
// ds_reads of the recycled buffer drain before its overwrite is issued.
// Prep & tail unchanged (single-variable). Numerics identical to R12.
//
// B=64, L=512, H=1024, Q=64, VA_H=256. Pairs = B*Q = 4096.

typedef __attribute__((ext_vector_type(4))) float f32x4;
typedef __attribute__((ext_vector_type(8))) short bf16x8;

#define NPAIR 4096
#define LSEQ 512
#define HDIM 1024
#define ZSPLIT 8

#if defined(__has_builtin)
#if __has_builtin(__builtin_amdgcn_global_load_lds)
#define HAVE_GLDS 1
#endif
#endif
#ifndef HAVE_GLDS
#define HAVE_GLDS 0
#endif

// Pack two f32 -> bf16 pair, round-to-nearest (half-up; differs from RNE only
// on exact ties, p~2^-16). v_perm_b32 grabs the two high halves.
__device__ __forceinline__ unsigned int pack2(float lo, float hi) {
  const unsigned int a = __float_as_uint(lo) + 0x8000u;
  const unsigned int b = __float_as_uint(hi) + 0x8000u;
  return __builtin_amdgcn_perm(b, a, 0x07060302u);
}
__device__ __forceinline__ unsigned short f2bf(float f) {
  return (unsigned short)((__float_as_uint(f) + 0x8000u) >> 16);
}
__device__ __forceinline__ float gelu(float x) {
  return 0.5f * x * (1.f + erff(x * 0.70710678118654752f));
}

// ---------------------------------------------------------------------------
// Merged prep: blocks [0,1024) = fused span pooling via MFMA; blocks
// [1024,1792) = W1 transpose; [1792,1824) = W2 transpose.
// Pool: one block per (batch, 64-col H-slice), 4/CU. Rows 0..63 = asp masks,
// 64..127 = opi. A-frags from span compares in registers; B staged f32->bf16
// transposed ([n][k]) double-buffered, 1 barrier/iter. Epilogue S[128][68].
// ---------------------------------------------------------------------------
__global__ __launch_bounds__(256, 4) void prep_kernel(
    const float* __restrict__ hs, const int* __restrict__ spans,
    const int* __restrict__ qmask, unsigned short* __restrict__ hpair,
    const float* __restrict__ W1, unsigned short* __restrict__ W1T,
    const float* __restrict__ W2, unsigned short* __restrict__ W2T) {
  __shared__ __align__(16) unsigned char smem[34816];  // max(2*64*40*2, 128*68*4)
  __shared__ float scl[128];
  const int tid = threadIdx.x;

  if (blockIdx.x >= 1024) {
    // ---- transpose path (f32 in -> bf16 out, transposed) ----
    float(*t)[33] = (float(*)[33])smem;  // 32x33 f32 = 4224 B
    const float* in;
    unsigned short* out;
    int C, R, c0, r0;
    int blk = blockIdx.x - 1024;
    if (blk < 768) {
      in = W1; out = W1T; R = 3072; C = 256;
      c0 = (blk & 7) * 32; r0 = (blk >> 3) * 32;
    } else {
      blk -= 768;
      in = W2; out = W2T; R = 256; C = 128;
      c0 = (blk & 3) * 32; r0 = (blk >> 2) * 32;
    }
    const int x = tid & 31, y = tid >> 5;  // (32, 8)
#pragma unroll
    for (int i = 0; i < 32; i += 8)
      t[y + i][x] = in[(size_t)(r0 + y + i) * C + c0 + x];
    __syncthreads();
#pragma unroll
    for (int i = 0; i < 32; i += 8)
      out[(size_t)(c0 + y + i) * R + r0 + x] = f2bf(t[x][y + i]);
    return;
  }

  // ---- pool path ----
  typedef unsigned short BlT[64][40];
  BlT* Bl = (BlT*)smem;                  // Bl[2][64][40]
  float(*S)[68] = (float(*)[68])smem;    // S[128][68] (epilogue only)

  const int b = blockIdx.x >> 4;
  const int n0 = (blockIdx.x & 15) * 64;
  const int lane = tid & 63;
  const int lm = lane & 15, quad = lane >> 4;
  const int wm = (tid >> 6) * 32;  // wave's mask-row base

  const bool is64 =
      (spans[1] == 0) && (spans[3] == 0) && (spans[5] == 0) && (spans[7] == 0);

  auto span_of = [&](int r, int& s, int& e) {
    const int q = r & 63, t = r >> 6;
    const int idx = (b * 64 + q) * 4 + t * 2;
    s = is64 ? spans[idx * 2] : spans[idx];
    e = is64 ? spans[idx * 2 + 2] : spans[idx + 1];
    if (s < 2) { s = 1; e = 1; }  // invalid -> [SEP]
  };
  int s0, e0, s1, e1;
  span_of(wm + lm, s0, e0);
  span_of(wm + 16 + lm, s1, e1);

  if (tid < 128) {
    int s, e;
    span_of(tid, s, e);
    const int c = (e >= s) ? (e - s + 1) : 0;
    const float sc = 1.f / (float)(c < 1 ? 1 : c);
    scl[tid] = (qmask[b * 64 + (tid & 63)] != 0) ? sc : 0.f;
  }

  f32x4 acc[2][4];
#pragma unroll
  for (int f = 0; f < 2; ++f)
#pragma unroll
    for (int g = 0; g < 4; ++g) acc[f][g] = f32x4{0.f, 0.f, 0.f, 0.f};

  const float* hsb = hs + (size_t)b * (LSEQ * HDIM);
  const int nl = tid & 63;        // staged column (wave-coalesced)
  const int kw = (tid >> 6) * 8;  // wave's k-offset within 32-chunk

  auto load8 = [&](int kbase, unsigned int (&tmp)[4]) {
    const float* src = hsb + (size_t)(kbase + kw) * HDIM + n0 + nl;
#pragma unroll
    for (int i = 0; i < 4; ++i) {
      const float f0 = src[(size_t)(2 * i) * HDIM];
      const float f1 = src[(size_t)(2 * i + 1) * HDIM];
      tmp[i] = pack2(f0, f1);
    }
  };

  unsigned int tmp[4];
  load8(0, tmp);
  *(uint4*)&Bl[0][nl][kw] = make_uint4(tmp[0], tmp[1], tmp[2], tmp[3]);

  for (int it = 0; it < 16; ++it) {
    const int k0 = it * 32;
    __syncthreads();  // buf[it&1] staged; prior reads of buf[(it+1)&1] done
    if (it < 15) load8(k0 + 32, tmp);

    bf16x8 a0, a1;
#pragma unroll
    for (int j = 0; j < 8; ++j) {
      const int k = k0 + quad * 8 + j;
      a0[j] = (short)((k >= s0 && k <= e0) ? 0x3F80 : 0);
      a1[j] = (short)((k >= s1 && k <= e1) ? 0x3F80 : 0);
    }
    const BlT& Bc = Bl[it & 1];
#pragma unroll
    for (int g = 0; g < 4; ++g) {
      bf16x8 bg = *(const bf16x8*)&Bc[g * 16 + lm][quad * 8];
      acc[0][g] = __builtin_amdgcn_mfma_f32_16x16x32_bf16(a0, bg, acc[0][g], 0, 0, 0);
      acc[1][g] = __builtin_amdgcn_mfma_f32_16x16x32_bf16(a1, bg, acc[1][g], 0, 0, 0);
    }
    if (it < 15) {
      *(uint4*)&Bl[(it + 1) & 1][nl][kw] = make_uint4(tmp[0], tmp[1], tmp[2], tmp[3]);
    }
  }

  __syncthreads();  // all MFMA LDS reads done before S overwrites Bl
  // C/D layout (m89): col = lane&15, row = quad*4 + reg.
#pragma unroll
  for (int f = 0; f < 2; ++f)
#pragma unroll
    for (int g = 0; g < 4; ++g)
#pragma unroll
      for (int r = 0; r < 4; ++r)
        S[wm + f * 16 + quad * 4 + r][g * 16 + lm] = acc[f][g][r];
  __syncthreads();

  // Store h_pair: thread q = tid>>2, 16-col group cg = (tid&3)*16.
  const int q = tid >> 2;
  const int cg = (tid & 3) * 16;
  const float sA = scl[q], sO = scl[64 + q];
  unsigned short* dst = hpair + (size_t)(b * 64 + q) * 3072 + n0 + cg;
#pragma unroll
  for (int h = 0; h < 2; ++h) {
    float a[8], o[8];
#pragma unroll
    for (int i = 0; i < 8; ++i) {
      a[i] = S[q][cg + h * 8 + i] * sA;
      o[i] = S[64 + q][cg + h * 8 + i] * sO;
    }
    uint4 wa, wo, wp;
    wa.x = pack2(a[0], a[1]); wa.y = pack2(a[2], a[3]);
    wa.z = pack2(a[4], a[5]); wa.w = pack2(a[6], a[7]);
    wo.x = pack2(o[0], o[1]); wo.y = pack2(o[2], o[3]);
    wo.z = pack2(o[4], o[5]); wo.w = pack2(o[6], o[7]);
    wp.x = pack2(a[0] * o[0], a[1] * o[1]); wp.y = pack2(a[2] * o[2], a[3] * o[3]);
    wp.z = pack2(a[4] * o[4], a[5] * o[5]); wp.w = pack2(a[6] * o[6], a[7] * o[7]);
    *(uint4*)(dst + h * 8) = wa;
    *(uint4*)(dst + 1024 + h * 8) = wo;
    *(uint4*)(dst + 2048 + h * 8) = wp;
  }
}

// ---------------------------------------------------------------------------
// Split-K GEMM1 partial, 64x256 tile, counted-vmcnt pipeline (T3+T4 min):
// 3-buffer LDS ring, prefetch depth 2. Per iter: [vmcnt(5); s_barrier] ->
// buf[t%3] ready (each wave waits only its own 5 global_load_lds for t;
// t+1's stay in flight) -> ds_read frags -> lgkmcnt(0)+sched_barrier ->
// s_barrier (all waves' reads of the recycle-target buffer drained) ->
// stage(t+2) -> 16 MFMA. vmcnt(0) only on the final iter. No per-iter full
// drain => load latency covered by ~2 iterations + co-resident block.
// Grid (64,1,8) = 512 blocks = 2/CU; LDS 60 KB (2 blocks = 120 <= 160).
// ---------------------------------------------------------------------------
__global__ __launch_bounds__(256, 2) void gemm_bt_64x256(
    const unsigned short* __restrict__ A, const unsigned short* __restrict__ Bt,
    float* __restrict__ P) {
  const int K = 3072, N = 256, KH = 384, NT = KH / 32;  // NT = 12
  __shared__ __align__(16) unsigned short Al[3][64][32];
  __shared__ __align__(16) unsigned short Bl[3][256][32];
  const int bm = blockIdx.x * 64;
  const int kz = blockIdx.z * KH;
  const int tid = threadIdx.x;
  const int wave = tid >> 6, lane = tid & 63;
  const int wn = wave * 64;  // wave's N-slice
  const int lm = lane & 15, lk = (lane >> 4) * 8;

  // Staging: wave stages A rows [wave*16,+16) (1 call) and B rows
  // [wave*64,+64) (4 calls); each call 16 rows x 32 cols = 1 KB, lane i ->
  // wave-uniform LDS base + 16*i (m104 constraint, layout proven R7-R12).
  const int srow = lane >> 2;          // 0..15
  const int scol = (lane & 3) * 8;
  const unsigned short* ga = A + (size_t)(bm + wave * 16 + srow) * K + kz + scol;
  const unsigned short* gb = Bt + (size_t)(wn + srow) * K + kz + scol;

  f32x4 acc[4][4];
#pragma unroll
  for (int i = 0; i < 4; ++i)
#pragma unroll
    for (int j = 0; j < 4; ++j) acc[i][j] = f32x4{0.f, 0.f, 0.f, 0.f};

  auto stage = [&](int u, int k0) {
#if HAVE_GLDS
    __builtin_amdgcn_global_load_lds(ga + k0, &Al[u][wave * 16][0], 16, 0, 0);
#pragma unroll
    for (int c = 0; c < 4; ++c)
      __builtin_amdgcn_global_load_lds(gb + (size_t)(c * 16) * K + k0,
                                       &Bl[u][wn + c * 16][0], 16, 0, 0);
#else
    *(uint4*)&Al[u][wave * 16 + srow][scol] = *(const uint4*)(ga + k0);
#pragma unroll
    for (int c = 0; c < 4; ++c)
      *(uint4*)&Bl[u][wn + c * 16 + srow][scol] =
          *(const uint4*)(gb + (size_t)(c * 16) * K + k0);
#endif
  };

#if HAVE_GLDS
  // -------- counted-vmcnt pipeline --------
  stage(0, 0);
  stage(1, 32);
  for (int t = 0; t < NT; ++t) {
    // buf[t%3]'s 5 loads are this wave's oldest outstanding VMEM ops.
    if (t + 1 < NT) {
      asm volatile("s_waitcnt vmcnt(5)" ::: "memory");
    } else {
      asm volatile("s_waitcnt vmcnt(0)" ::: "memory");
    }
    __builtin_amdgcn_s_barrier();  // all waves: buf[t%3] fully landed
    const int u = t % 3;
    bf16x8 af[4], bf[4];
#pragma unroll
    for (int i = 0; i < 4; ++i) {
      af[i] = *(const bf16x8*)&Al[u][i * 16 + lm][lk];
      bf[i] = *(const bf16x8*)&Bl[u][wn + i * 16 + lm][lk];
    }
    // Drain this wave's ds_reads, then barrier: after it, NO wave still
    // reads buf[(t+2)%3] (== buf[(t-1)%3], consumed last iter), so the
    // stage below may overwrite it.
    asm volatile("s_waitcnt lgkmcnt(0)" ::: "memory");
    __builtin_amdgcn_sched_barrier(0);
    __builtin_amdgcn_s_barrier();
    if (t + 2 < NT) stage((t + 2) % 3, (t + 2) * 32);
#pragma unroll
    for (int i = 0; i < 4; ++i)
#pragma unroll
      for (int j = 0; j < 4; ++j)
        acc[i][j] = __builtin_amdgcn_mfma_f32_16x16x32_bf16(af[i], bf[j],
                                                            acc[i][j], 0, 0, 0);
  }
#else
  // -------- fallback: classic double-buffer with __syncthreads --------
  stage(0, 0);
  for (int t = 0; t < NT; ++t) {
    __syncthreads();
    if (t + 1 < NT) stage((t + 1) % 3, (t + 1) * 32);
    const int u = t % 3;
    bf16x8 af[4], bf[4];
#pragma unroll
    for (int i = 0; i < 4; ++i) {
      af[i] = *(const bf16x8*)&Al[u][i * 16 + lm][lk];
      bf[i] = *(const bf16x8*)&Bl[u][wn + i * 16 + lm][lk];
    }
#pragma unroll
    for (int i = 0; i < 4; ++i)
#pragma unroll
      for (int j = 0; j < 4; ++j)
        acc[i][j] = __builtin_amdgcn_mfma_f32_16x16x32_bf16(af[i], bf[j],
                                                            acc[i][j], 0, 0, 0);
    __syncthreads();
  }
#endif

  float* Pz = P + (size_t)blockIdx.z * NPAIR * N;
  const int rq = (lane >> 4) << 2;
#pragma unroll
  for (int i = 0; i < 4; ++i)
#pragma unroll
    for (int j = 0; j < 4; ++j) {
      const int r0 = bm + i * 16 + rq;
      const int c0 = wn + j * 16 + lm;
#pragma unroll
      for (int r = 0; r < 4; ++r)
        Pz[(size_t)(r0 + r) * N + c0] = acc[i][j][r];
    }
}

// ---------------------------------------------------------------------------
// Fused tail: split-K reduce (8 partials) + b1 + gelu -> x1 tile (LDS),
// GEMM2 (16x128, K=256) with B-frags from W2T global (L2-resident),
// gelu+b2 -> S2, head dot W3, sigmoid*8+1, *qmask.
// 256 blocks x 16 pairs = 1 block/CU. ONE barrier before the K-loop.
// ---------------------------------------------------------------------------
__global__ __launch_bounds__(256) void tail_kernel(
    const float* __restrict__ P, const float* __restrict__ b1,
    const unsigned short* __restrict__ W2T, const float* __restrict__ b2,
    const float* __restrict__ W3, const float* __restrict__ b3,
    const int* __restrict__ qmask, float* __restrict__ out) {
  __shared__ __align__(16) unsigned short Al[16 * 264];  // x1 tile, 528B rows
  __shared__ float S2[16][132];                          // x2 tile f32
  __shared__ float w3[256];

  const int m0 = blockIdx.x * 16;
  const int tid = threadIdx.x;
  const int wave = tid >> 6, lane = tid & 63;
  const int lm = lane & 15, quad = lane >> 4;
  const int wn = wave * 32;  // wave's 32-col slice of N=128

  w3[tid] = W3[tid];  // 128x2 f32

  // --- Stage x1 tile: x1[r][k] = gelu(sum_z P[z] + b1). 16 elems/thread,
  // coalesced float4 reads of P.
  {
    const int row = tid >> 4;   // 0..15
    const int slot = tid & 15;  // 8-elem slot
#pragma unroll
    for (int ss = 0; ss < 2; ++ss) {
      const int s = slot + ss * 16;  // 0..31
      const float* pb = P + (size_t)(m0 + row) * 256 + s * 8;
      float v[8];
      {
        float4 ba = *(const float4*)(b1 + s * 8);
        float4 bb = *(const float4*)(b1 + s * 8 + 4);
        v[0] = ba.x; v[1] = ba.y; v[2] = ba.z; v[3] = ba.w;
        v[4] = bb.x; v[5] = bb.y; v[6] = bb.z; v[7] = bb.w;
      }
#pragma unroll
      for (int z = 0; z < ZSPLIT; ++z) {
        const float* pz = pb + (size_t)z * ((size_t)NPAIR * 256);
        float4 a0 = *(const float4*)pz;
        float4 a1 = *(const float4*)(pz + 4);
        v[0] += a0.x; v[1] += a0.y; v[2] += a0.z; v[3] += a0.w;
        v[4] += a1.x; v[5] += a1.y; v[6] += a1.z; v[7] += a1.w;
      }
      uint4 w;
      w.x = pack2(gelu(v[0]), gelu(v[1]));
      w.y = pack2(gelu(v[2]), gelu(v[3]));
      w.z = pack2(gelu(v[4]), gelu(v[5]));
      w.w = pack2(gelu(v[6]), gelu(v[7]));
      *(uint4*)((char*)Al + (size_t)row * 528 + s * 16) = w;
    }
  }
  __syncthreads();  // Al ready; LDS read-only from here

  // --- GEMM2: M=16 (1 frag), N=128 (2 frags/wave), K=256 (8 steps).
  // B-frags straight from W2T[n][k] global (row n = wn+g*16+lm, 16B-aligned).
  f32x4 acc[2];
  acc[0] = f32x4{0.f, 0.f, 0.f, 0.f};
  acc[1] = f32x4{0.f, 0.f, 0.f, 0.f};
#pragma unroll
  for (int ks = 0; ks < 8; ++ks) {
    bf16x8 a = *(const bf16x8*)((char*)Al + (size_t)lm * 528 + ks * 64 + quad * 16);
#pragma unroll
    for (int g = 0; g < 2; ++g) {
      const int n = wn + g * 16 + lm;
      bf16x8 b = *(const bf16x8*)(W2T + (size_t)n * 256 + ks * 32 + quad * 8);
      acc[g] = __builtin_amdgcn_mfma_f32_16x16x32_bf16(a, b, acc[g], 0, 0, 0);
    }
  }

  // --- x2 = gelu(acc + b2). C/D: col = lane&15, row = quad*4 + reg.
#pragma unroll
  for (int g = 0; g < 2; ++g) {
    const int col = wn + g * 16 + lm;
    const float bc = b2[col];
#pragma unroll
    for (int r = 0; r < 4; ++r) S2[quad * 4 + r][col] = gelu(acc[g][r] + bc);
  }
  __syncthreads();

  // --- Head: 128 threads, (row, o) each split 4-way over K=128, shfl-reduce.
  if (tid < 128) {
    const int row = tid >> 3, o = (tid >> 2) & 1, q4 = tid & 3;
    float part = 0.f;
#pragma unroll 8
    for (int c = q4; c < 128; c += 4) part += S2[row][c] * w3[c * 2 + o];
    part += __shfl_xor(part, 1);
    part += __shfl_xor(part, 2);
    if (q4 == 0) {
      const int pair = m0 + row;
      const float a = part + b3[o];
      const float qmf = (float)qmask[pair];
      out[pair * 2 + o] = ((1.f / (1.f + expf(-a))) * 8.f + 1.f) * qmf;
    }
  }
}

// ---------------------------------------------------------------------------
extern "C" void kernel_launch(void* const* d_in, const int* in_sizes, int n_in,
                              void* d_out, int out_size, void* d_ws,
                              size_t ws_size, hipStream_t stream) {
  const float* hs = (const float*)d_in[0];   // f32 64x512x1024
  const int* spans = (const int*)d_in[1];
  const int* qmask = (const int*)d_in[2];
  const float* W1 = (const float*)d_in[3];   // f32 3072x256
  const float* b1 = (const float*)d_in[4];
  const float* W2 = (const float*)d_in[5];   // f32 256x128
  const float* b2 = (const float*)d_in[6];
  const float* W3 = (const float*)d_in[7];   // f32 128x2
  const float* b3 = (const float*)d_in[8];
  float* out = (float*)d_out;

  const size_t HPAIR_B = 25165824;  // 4096*3072 bf16
  const size_t P_B = 33554432;      // 8 x 4096*256 f32
  const size_t W1T_B = 1572864;     // 256*3072 bf16

  char* ws = (char*)d_ws;
  size_t off = 0;
  unsigned short* hpair = (unsigned short*)(ws + off); off += HPAIR_B;
  float* P = (float*)(ws + off);                       off += P_B;
  unsigned short* W1T = (unsigned short*)(ws + off);   off += W1T_B;
  unsigned short* W2T = (unsigned short*)(ws + off);

  prep_kernel<<<1824, 256, 0, stream>>>(hs, spans, qmask, hpair, W1, W1T, W2, W2T);
  gemm_bt_64x256<<<dim3(64, 1, ZSPLIT), 256, 0, stream>>>(hpair, W1T, P);
  tail_kernel<<<256, 256, 0, stream>>>(P, b1, W2T, b2, W3, b3, qmask, out);
}